// Round 10
// baseline (216.773 us; speedup 1.0000x reference)
//
#include <hip/hip_runtime.h>
#include <cmath>

#define EPSV 1e-5f
using f4 = float4;

typedef __attribute__((ext_vector_type(8))) short bfrag;   // 8 bf16 (4 VGPRs)
typedef __attribute__((ext_vector_type(4))) float ffrag;   // 4 fp32 acc

// ---- ws layout (float offsets) ----
#define WS_SKV   0           // [4][256]
#define WS_SHKV  1024        // [4][256]
#define WS_SH    2048        // [4][256]
#define WS_SHH   3072        // [4][256]
#define WS_A     4096        // [4][4][256]
#define WS_R     8192        // ushort view: racc partials [2][4096][4][256] bf16
#define WS_HT    4202496     // [4096][256] fp32 htok
#define WS_L     5251072     // [2][4096][4] fp32 l partials
#define WS_G     6299648
#define WS_GB    WS_G                   // ushort[4096*1024]  g bf16
#define WS_HNB   (WS_G + 2097152)       // ushort[4096*256]   hn bf16
#define WS_W1T   (WS_G + 2621440)       // ushort[1024*256]   W1^T bf16 [n][k]
#define WS_W2T   (WS_G + 2752512)       // ushort[256*1024]   W2^T bf16 [n][k]
#define WS_MT    (WS_G + 2883584)       // ushort[256*1024]   M^T bf16 [j][h*256+d]

#define FMA8(acc, s, wa, wb) \
  acc[0]=fmaf((s),(wa).x,acc[0]); acc[1]=fmaf((s),(wa).y,acc[1]); \
  acc[2]=fmaf((s),(wa).z,acc[2]); acc[3]=fmaf((s),(wa).w,acc[3]); \
  acc[4]=fmaf((s),(wb).x,acc[4]); acc[5]=fmaf((s),(wb).y,acc[5]); \
  acc[6]=fmaf((s),(wb).z,acc[6]); acc[7]=fmaf((s),(wb).w,acc[7]);

#define DOT8(res, v, wa, wb) \
  res = fmaf((v)[0],(wa).x,res); res = fmaf((v)[1],(wa).y,res); \
  res = fmaf((v)[2],(wa).z,res); res = fmaf((v)[3],(wa).w,res); \
  res = fmaf((v)[4],(wb).x,res); res = fmaf((v)[5],(wb).y,res); \
  res = fmaf((v)[6],(wb).z,res); res = fmaf((v)[7],(wb).w,res);

__device__ __forceinline__ float bfly32(float v){
  v += __shfl_xor(v, 1);  v += __shfl_xor(v, 2);  v += __shfl_xor(v, 4);
  v += __shfl_xor(v, 8);  v += __shfl_xor(v, 16);
  return v;
}

// DPP-based 32-lane allreduce (round-8 verified).
template<int CTRL>
__device__ __forceinline__ float dpp_add(float v){
  int x = __builtin_bit_cast(int, v);
  int y = __builtin_amdgcn_update_dpp(0, x, CTRL, 0xf, 0xf, true);
  return v + __builtin_bit_cast(float, y);
}
__device__ __forceinline__ float red32(float v){
  v = dpp_add<0xB1>(v);
  v = dpp_add<0x4E>(v);
  v = dpp_add<0x124>(v);
  v = dpp_add<0x128>(v);
  v += __shfl_xor(v, 16);
  return v;
}

__device__ __forceinline__ float gelu_fast(float x){
  float z2 = 1.5957691216057308f*(x + 0.044715f*x*x*x);
  return x / (1.0f + __expf(-z2));
}

__device__ __forceinline__ unsigned short f2bf(float x){
  union { float f; unsigned u; } v; v.f = x;
  unsigned r = v.u + 0x7fffu + ((v.u >> 16) & 1u);
  return (unsigned short)(r >> 16);
}
__device__ __forceinline__ float bfu(unsigned short u){
  union { unsigned u; float f; } v; v.u = ((unsigned)u) << 16; return v.f;
}
__device__ __forceinline__ ushort4 comb4(ushort4 a, ushort4 b, float inv){
  ushort4 r;
  r.x = f2bf((bfu(a.x)+bfu(b.x))*inv);
  r.y = f2bf((bfu(a.y)+bfu(b.y))*inv);
  r.z = f2bf((bfu(a.z)+bfu(b.z))*inv);
  r.w = f2bf((bfu(a.w)+bfu(b.w))*inv);
  return r;
}

// ------------------------------------------------------------------
// KPREP: merged weight prep + per-(b,h) setup.
// blk<64: W1 conv+T; blk<128: W2 conv+T; blk<384: M^T=Wv@Wo;
// blk>=384 (16 blocks): k0_all body. grid=400, block=256.
// All bodies verified in rounds 5-8.
// ------------------------------------------------------------------
__global__ __launch_bounds__(256) void kprep(
  const float* __restrict__ W1, const float* __restrict__ W2,
  const float* __restrict__ Wv, const float* __restrict__ Wo,
  const float* __restrict__ ctx, const float* __restrict__ q_emb,
  const float* __restrict__ Wkv, const float* __restrict__ bkv,
  const float* __restrict__ Wqc, const float* __restrict__ bqc,
  const float* __restrict__ Whc, const float* __restrict__ bhc,
  const float* __restrict__ Wq,  const float* __restrict__ Wk,
  float* __restrict__ ws)
{
  const int tid = threadIdx.x;
  int blk = blockIdx.x;
  __shared__ union {
    unsigned short lt[64][68];
    struct { float wvs[4*64]; float wos[64*256]; } m;
    struct { float c[64], qn[256], ph[256], qh64[64], red[8]; } z;
  } sm;

  if (blk < 128){
    const float* src; unsigned short* dst; int K, N, K0, N0;
    if (blk < 64){
      src = W1; dst = (unsigned short*)(ws + WS_W1T);
      K = 256; N = 1024; K0 = (blk >> 4)*64; N0 = (blk & 15)*64;
    } else {
      blk -= 64;
      src = W2; dst = (unsigned short*)(ws + WS_W2T);
      K = 1024; N = 256; K0 = (blk >> 2)*64; N0 = (blk & 3)*64;
    }
    #pragma unroll
    for (int i=0;i<4;++i){
      int r = i*16 + (tid>>4);
      int c = (tid&15)*4;
      f4 v = *(const f4*)(src + (size_t)(K0+r)*N + N0 + c);
      sm.lt[r][c]   = f2bf(v.x); sm.lt[r][c+1] = f2bf(v.y);
      sm.lt[r][c+2] = f2bf(v.z); sm.lt[r][c+3] = f2bf(v.w);
    }
    __syncthreads();
    #pragma unroll
    for (int i=0;i<4;++i){
      int n  = i*16 + (tid>>4);
      int kc = (tid&15)*4;
      ushort4 u;
      u.x = sm.lt[kc][n]; u.y = sm.lt[kc+1][n]; u.z = sm.lt[kc+2][n]; u.w = sm.lt[kc+3][n];
      *(ushort4*)(dst + (size_t)(N0+n)*K + K0 + kc) = u;
    }
  } else if (blk < 384){
    blk -= 128;
    const int h   = blk >> 6;
    const int dg4 = blk & 63;
    {
      int d = tid >> 6, e = tid & 63;
      sm.m.wvs[d*64+e] = Wv[(size_t)(dg4*4 + d)*256 + h*64 + e];
    }
    {
      int e = tid >> 2, c = (tid & 3)*64;
      const float* src = Wo + (size_t)(h*64 + e)*256 + c;
      #pragma unroll
      for (int i=0;i<16;++i)
        *(f4*)&sm.m.wos[e*256 + c + i*4] = *(const f4*)(src + i*4);
    }
    __syncthreads();
    float acc[4] = {};
    for (int e=0;e<64;++e){
      float wo = sm.m.wos[e*256 + tid];
      acc[0] = fmaf(sm.m.wvs[0*64+e], wo, acc[0]);
      acc[1] = fmaf(sm.m.wvs[1*64+e], wo, acc[1]);
      acc[2] = fmaf(sm.m.wvs[2*64+e], wo, acc[2]);
      acc[3] = fmaf(sm.m.wvs[3*64+e], wo, acc[3]);
    }
    unsigned short* Mt = (unsigned short*)(ws + WS_MT);
    ushort4 u;
    u.x = f2bf(acc[0]); u.y = f2bf(acc[1]); u.z = f2bf(acc[2]); u.w = f2bf(acc[3]);
    *(ushort4*)(Mt + (size_t)tid*1024 + h*256 + dg4*4) = u;
  } else {
    blk -= 384;
    const int b = blk >> 2, h = blk & 3;
    if (tid < 64) sm.z.c[tid] = ctx[b*64 + tid];
    __syncthreads();

    float skv = bkv[tid],      shkv = bkv[256+tid];
    float sq  = bqc[tid],      shq  = bqc[256+tid];
    float sh  = bhc[tid],      shh  = bhc[256+tid];
    #pragma unroll 8
    for (int j=0;j<64;++j){
      float cj = sm.z.c[j];
      skv  = fmaf(cj, Wkv[j*512 + tid],       skv);
      shkv = fmaf(cj, Wkv[j*512 + 256 + tid], shkv);
      sq   = fmaf(cj, Wqc[j*512 + tid],       sq);
      shq  = fmaf(cj, Wqc[j*512 + 256 + tid], shq);
      sh   = fmaf(cj, Whc[j*512 + tid],       sh);
      shh  = fmaf(cj, Whc[j*512 + 256 + tid], shh);
    }
    if (h == 0){
      ws[WS_SKV  + b*256 + tid] = skv;
      ws[WS_SHKV + b*256 + tid] = shkv;
      ws[WS_SH   + b*256 + tid] = sh;
      ws[WS_SHH  + b*256 + tid] = shh;
    }

    float qe = q_emb[tid];
    float s1r = qe, s2r = qe*qe;
    for (int mm=1;mm<64;mm<<=1){ s1r += __shfl_xor(s1r,mm); s2r += __shfl_xor(s2r,mm); }
    int wv = tid>>6, ln = tid&63;
    if (ln==0){ sm.z.red[wv*2]=s1r; sm.z.red[wv*2+1]=s2r; }
    __syncthreads();
    float S1 = sm.z.red[0]+sm.z.red[2]+sm.z.red[4]+sm.z.red[6];
    float S2 = sm.z.red[1]+sm.z.red[3]+sm.z.red[5]+sm.z.red[7];
    float mean = S1*(1.0f/256.0f);
    float var  = S2*(1.0f/256.0f) - mean*mean;
    float rs   = rsqrtf(var + EPSV);
    sm.z.qn[tid] = (qe-mean)*rs*(1.0f+sq) + shq;
    __syncthreads();

    {
      const int t = tid & 63, ks = tid >> 6;
      float p = 0.f;
      const float* wq = Wq + (size_t)(ks*64)*256 + h*64 + t;
      #pragma unroll 8
      for (int d=0; d<64; ++d) p = fmaf(sm.z.qn[ks*64+d], wq[d*256], p);
      sm.z.ph[tid] = p;
    }
    __syncthreads();
    if (tid < 64) sm.z.qh64[tid] = sm.z.ph[tid] + sm.z.ph[64+tid] + sm.z.ph[128+tid] + sm.z.ph[192+tid];
    __syncthreads();

    {
      float a = 0.f;
      const float* wkr = Wk + (size_t)tid*256 + h*64;
      #pragma unroll
      for (int e4=0; e4<16; ++e4){
        f4 wv4 = *(const f4*)(wkr + e4*4);
        a = fmaf(sm.z.qh64[e4*4+0], wv4.x, a);
        a = fmaf(sm.z.qh64[e4*4+1], wv4.y, a);
        a = fmaf(sm.z.qh64[e4*4+2], wv4.z, a);
        a = fmaf(sm.z.qh64[e4*4+3], wv4.w, a);
      }
      ws[WS_A + b*1024 + h*256 + tid] = 0.125f*a;
    }
  }
}

// ------------------------------------------------------------------
// K1F v4: token-pairing. 16 tokens per block (thread handles t, t+8
// with one W read), 16 f per block (2 f-halves), grid=512.
// Math identical to round-8-verified k1f; W LDS reads serve 2 tokens.
// ------------------------------------------------------------------
__global__ __launch_bounds__(256,2) void k1f_attn(
  const float* __restrict__ x, const int* __restrict__ idx,
  const float* __restrict__ Wp, const float* __restrict__ Bp,
  float* __restrict__ ws)
{
  __shared__ float xs[4096];      // [16 t][256]
  __shared__ float wls[4096];     // [2 f][8 i][256 d]

  const int tid = threadIdx.x;
  const int p0  = (blockIdx.x >> 1) * 16;
  const int half= blockIdx.x & 1;
  const int f0  = half * 16;
  const int b   = p0 >> 10;
  const int t   = tid >> 5;
  const int dg  = tid & 31;
  const int dA  = 4*dg, dB = 128 + 4*dg;

  {
    const float* xg = x + (size_t)p0*256 + tid*8;
    f4 a  = *(const f4*)xg;
    f4 bq = *(const f4*)(xg + 4);
    *(f4*)&xs[tid*8]     = a;
    *(f4*)&xs[tid*8 + 4] = bq;
    f4 a2  = *(const f4*)(xg + 2048);
    f4 bq2 = *(const f4*)(xg + 2048 + 4);
    *(f4*)&xs[2048 + tid*8]     = a2;
    *(f4*)&xs[2048 + tid*8 + 4] = bq2;
  }
  f4 Ar[4][2];
  #pragma unroll
  for (int h=0;h<4;++h){
    Ar[h][0] = *(const f4*)(ws + WS_A + b*1024 + h*256 + dA);
    Ar[h][1] = *(const f4*)(ws + WS_A + b*1024 + h*256 + dB);
  }

  f4 skA = *(const f4*)(ws + WS_SKV  + b*256 + dA);
  f4 skB = *(const f4*)(ws + WS_SKV  + b*256 + dB);
  f4 shA = *(const f4*)(ws + WS_SHKV + b*256 + dA);
  f4 shB = *(const f4*)(ws + WS_SHKV + b*256 + dB);
  float coef[8] = {1.f+skA.x,1.f+skA.y,1.f+skA.z,1.f+skA.w,
                   1.f+skB.x,1.f+skB.y,1.f+skB.z,1.f+skB.w};
  float shk[8]  = {shA.x,shA.y,shA.z,shA.w, shB.x,shB.y,shB.z,shB.w};

  int r0 = idx[f0], r1 = idx[f0+1];
  f4 u0 = *(const f4*)(Wp + (size_t)r0*2048 + tid*8);
  f4 u1 = *(const f4*)(Wp + (size_t)r0*2048 + tid*8 + 4);
  f4 u2 = *(const f4*)(Wp + (size_t)r1*2048 + tid*8);
  f4 u3 = *(const f4*)(Wp + (size_t)r1*2048 + tid*8 + 4);

  float l[2][4] = {};
  float racc[2][4][8] = {};

  for (int fi = 0; fi < 8; ++fi){
    const int f = f0 + fi*2;
    __syncthreads();
    wls[0*256+tid]=u0.x; wls[1*256+tid]=u0.y; wls[2*256+tid]=u0.z; wls[3*256+tid]=u0.w;
    wls[4*256+tid]=u1.x; wls[5*256+tid]=u1.y; wls[6*256+tid]=u1.z; wls[7*256+tid]=u1.w;
    wls[2048+0*256+tid]=u2.x; wls[2048+1*256+tid]=u2.y;
    wls[2048+2*256+tid]=u2.z; wls[2048+3*256+tid]=u2.w;
    wls[2048+4*256+tid]=u3.x; wls[2048+5*256+tid]=u3.y;
    wls[2048+6*256+tid]=u3.z; wls[2048+7*256+tid]=u3.w;
    __syncthreads();

    f4 ba0 = *(const f4*)(Bp + (size_t)r0*256 + dA);
    f4 bb0 = *(const f4*)(Bp + (size_t)r0*256 + dB);
    f4 ba1 = *(const f4*)(Bp + (size_t)r1*256 + dA);
    f4 bb1 = *(const f4*)(Bp + (size_t)r1*256 + dB);

    const int fn = (fi < 7) ? f + 2 : f0;
    int rn0 = idx[fn], rn1 = idx[fn+1];
    u0 = *(const f4*)(Wp + (size_t)rn0*2048 + tid*8);
    u1 = *(const f4*)(Wp + (size_t)rn0*2048 + tid*8 + 4);
    u2 = *(const f4*)(Wp + (size_t)rn1*2048 + tid*8);
    u3 = *(const f4*)(Wp + (size_t)rn1*2048 + tid*8 + 4);

    #pragma unroll
    for (int sub=0; sub<2; ++sub){
      const float* wrow = wls + sub*2048;
      const int fc = f + sub;
      f4 ba = sub ? ba1 : ba0;
      f4 bb = sub ? bb1 : bb0;

      float xf0[8], xf1[8];
      {
        f4 xa = *(const f4*)&xs[t*256 + fc*8];
        f4 xb = *(const f4*)&xs[t*256 + fc*8 + 4];
        xf0[0]=xa.x; xf0[1]=xa.y; xf0[2]=xa.z; xf0[3]=xa.w;
        xf0[4]=xb.x; xf0[5]=xb.y; xf0[6]=xb.z; xf0[7]=xb.w;
        f4 xc = *(const f4*)&xs[(t+8)*256 + fc*8];
        f4 xd = *(const f4*)&xs[(t+8)*256 + fc*8 + 4];
        xf1[0]=xc.x; xf1[1]=xc.y; xf1[2]=xc.z; xf1[3]=xc.w;
        xf1[4]=xd.x; xf1[5]=xd.y; xf1[6]=xd.z; xf1[7]=xd.w;
      }

      float val[2][8] = {};
      #pragma unroll
      for (int i=0;i<8;++i){
        f4 wa  = *(const f4*)&wrow[i*256 + dA];
        f4 wbv = *(const f4*)&wrow[i*256 + dB];
        FMA8(val[0], xf0[i], wa, wbv);
        FMA8(val[1], xf1[i], wa, wbv);
      }

      float off[8] = {shk[0]+ba.x, shk[1]+ba.y, shk[2]+ba.z, shk[3]+ba.w,
                      shk[4]+bb.x, shk[5]+bb.y, shk[6]+bb.z, shk[7]+bb.w};

      #pragma unroll
      for (int tt=0; tt<2; ++tt){
        float s=0.f, ss=0.f;
        #pragma unroll
        for (int jj=0;jj<8;++jj){ s += val[tt][jj]; ss = fmaf(val[tt][jj],val[tt][jj],ss); }
        s = red32(s); ss = red32(ss);
        float mean = s*(1.f/256.f);
        float var  = ss*(1.f/256.f) - mean*mean;
        float rsg  = rsqrtf(var + EPSV);
        float mrs  = mean*rsg;

        float kvl[8];
        #pragma unroll
        for (int jj=0;jj<8;++jj)
          kvl[jj] = fmaf(fmaf(val[tt][jj], rsg, -mrs), coef[jj], off[jj]);

        #pragma unroll
        for (int h=0;h<4;++h){
          float lg = 0.f;
          DOT8(lg, kvl, Ar[h][0], Ar[h][1]);
          lg = red32(lg);
          float pp = __expf(lg);
          l[tt][h] += pp;
          #pragma unroll
          for (int jj=0;jj<8;++jj)
            racc[tt][h][jj] = fmaf(pp, kvl[jj], racc[tt][h][jj]);
        }
      }
    }
    r0 = rn0; r1 = rn1;
  }

  unsigned short* Pr = (unsigned short*)(ws + WS_R);
  #pragma unroll
  for (int tt=0; tt<2; ++tt){
    size_t base = (size_t)(half*4096 + p0 + t + tt*8) * 1024;
    #pragma unroll
    for (int h=0;h<4;++h){
      ushort4 ua, ub;
      ua.x=f2bf(racc[tt][h][0]); ua.y=f2bf(racc[tt][h][1]);
      ua.z=f2bf(racc[tt][h][2]); ua.w=f2bf(racc[tt][h][3]);
      ub.x=f2bf(racc[tt][h][4]); ub.y=f2bf(racc[tt][h][5]);
      ub.z=f2bf(racc[tt][h][6]); ub.w=f2bf(racc[tt][h][7]);
      *(ushort4*)(Pr + base + h*256 + dA) = ua;
      *(ushort4*)(Pr + base + h*256 + dB) = ub;
    }
  }
  if (dg == 0){
    float* Lp = ws + WS_L;
    #pragma unroll
    for (int tt=0; tt<2; ++tt)
      #pragma unroll
      for (int h=0;h<4;++h)
        Lp[(size_t)(half*4096 + p0 + t + tt*8)*4 + h] = l[tt][h];
  }
}

// ------------------------------------------------------------------
// K2E: o2 = ((P0+P1)/l)@Mt^T, htok = o2+q_emb, hn = CLN(htok).
// One block per 16 tokens (grid=256), full N=256 per block so LN
// completes in-block. 4 waves, wave = 16m x 64n (4 b-frags).
// B-staging uses f4 loads (8 ushorts each) at offsets {0,8,16,24}
// -- full 32-k coverage (R9 bug: ushort4 loads left gaps -> NaN).
// ------------------------------------------------------------------
__global__ __launch_bounds__(256) void k2e_mfma(
  const float* __restrict__ q_emb, float* __restrict__ ws)
{
  __shared__ unsigned short aT[2][16*40];
  __shared__ unsigned short bT[2][256*40];
  __shared__ float invs[64];      // [16 t][4 h]
  __shared__ float red[128];      // [4 wave][16 row][2]
  const unsigned short* P0 = (const unsigned short*)(ws + WS_R);
  const unsigned short* P1 = P0 + 4194304;
  const unsigned short* mt = (const unsigned short*)(ws + WS_MT);
  const float* Lp = ws + WS_L;

  const int tid = threadIdx.x;
  const int M0  = blockIdx.x * 16;
  const int b   = M0 >> 10;
  const int lane = tid & 63;
  const int wid  = tid >> 6;          // n-quarter
  const int m16  = lane & 15, q = lane >> 4;

  const int sa_m = tid >> 3, sa_k = (tid & 7) * 4;
  if (tid < 64){
    int lt = tid >> 2, h = tid & 3;
    invs[tid] = 1.f / (Lp[(size_t)(M0 + lt)*4 + h] +
                       Lp[(size_t)(4096 + M0 + lt)*4 + h]);
  }

  ushort4 ua0, ua1;
  if (tid < 128){
    ua0 = *(const ushort4*)(P0 + (size_t)(M0 + sa_m)*1024 + sa_k);
    ua1 = *(const ushort4*)(P1 + (size_t)(M0 + sa_m)*1024 + sa_k);
  }
  f4 ub[4];   // each f4 = 8 ushorts; offsets 0,8,16,24 cover all 32 k
  #pragma unroll
  for (int i=0;i<4;++i)
    ub[i] = *(const f4*)(mt + (size_t)tid*1024 + i*8);
  __syncthreads();   // invs visible

  ffrag acc[4];
  #pragma unroll
  for (int j=0;j<4;++j) acc[j] = (ffrag){0.f,0.f,0.f,0.f};

  for (int ks=0; ks<32; ++ks){
    const int buf = ks & 1;
    if (tid < 128){
      float inv = invs[sa_m*4 + (ks >> 3)];
      *(ushort4*)&aT[buf][sa_m*40 + sa_k] = comb4(ua0, ua1, inv);
    }
    #pragma unroll
    for (int i=0;i<4;++i)
      *(f4*)&bT[buf][tid*40 + i*8] = ub[i];
    __syncthreads();
    int kn = (ks < 31) ? ks+1 : 31;
    if (tid < 128){
      ua0 = *(const ushort4*)(P0 + (size_t)(M0 + sa_m)*1024 + kn*32 + sa_k);
      ua1 = *(const ushort4*)(P1 + (size_t)(M0 + sa_m)*1024 + kn*32 + sa_k);
    }
    #pragma unroll
    for (int i=0;i<4;++i)
      ub[i] = *(const f4*)(mt + (size_t)tid*1024 + kn*32 + i*8);

    bfrag af = *(const bfrag*)&aT[buf][m16*40 + q*8];
    #pragma unroll
    for (int j=0;j<4;++j){
      bfrag bf = *(const bfrag*)&bT[buf][(wid*64 + j*16 + m16)*40 + q*8];
      acc[j] = __builtin_amdgcn_mfma_f32_16x16x32_bf16(bf, af, acc[j], 0, 0, 0);
    }
  }

  // epilogue: ht = o2 + q_emb; LN across the row (4 waves x 64 cols)
  float htv[4][4];
  float s = 0.f, ss = 0.f;
  #pragma unroll
  for (int j=0;j<4;++j){
    const int n4 = wid*64 + j*16 + q*4;
    f4 qe = *(const f4*)(q_emb + n4);
    htv[j][0] = acc[j][0] + qe.x;
    htv[j][1] = acc[j][1] + qe.y;
    htv[j][2] = acc[j][2] + qe.z;
    htv[j][3] = acc[j][3] + qe.w;
    #pragma unroll
    for (int r=0;r<4;++r){ s += htv[j][r]; ss = fmaf(htv[j][r], htv[j][r], ss); }
  }
  s  += __shfl_xor(s, 16);  s  += __shfl_xor(s, 32);
  ss += __shfl_xor(ss, 16); ss += __shfl_xor(ss, 32);
  if (q == 0){ red[wid*32 + m16*2] = s; red[wid*32 + m16*2 + 1] = ss; }
  __syncthreads();
  float S  = red[m16*2]     + red[32 + m16*2]     + red[64 + m16*2]     + red[96 + m16*2];
  float SS = red[m16*2 + 1] + red[32 + m16*2 + 1] + red[64 + m16*2 + 1] + red[96 + m16*2 + 1];
  float mean = S*(1.f/256.f);
  float var  = SS*(1.f/256.f) - mean*mean;
  float rsg  = rsqrtf(var + EPSV);

  unsigned short* hnb = (unsigned short*)(ws + WS_HNB);
  const int m = M0 + m16;
  #pragma unroll
  for (int j=0;j<4;++j){
    const int n4 = wid*64 + j*16 + q*4;
    f4 sH = *(const f4*)(ws + WS_SH  + b*256 + n4);
    f4 hH = *(const f4*)(ws + WS_SHH + b*256 + n4);
    float hn0 = (htv[j][0]-mean)*rsg*(1.f+sH.x) + hH.x;
    float hn1 = (htv[j][1]-mean)*rsg*(1.f+sH.y) + hH.y;
    float hn2 = (htv[j][2]-mean)*rsg*(1.f+sH.z) + hH.z;
    float hn3 = (htv[j][3]-mean)*rsg*(1.f+sH.w) + hH.w;
    *(f4*)(ws + WS_HT + (size_t)m*256 + n4) =
      make_float4(htv[j][0], htv[j][1], htv[j][2], htv[j][3]);
    ushort4 u;
    u.x = f2bf(hn0); u.y = f2bf(hn1); u.z = f2bf(hn2); u.w = f2bf(hn3);
    *(ushort4*)(hnb + (size_t)m*256 + n4) = u;
  }
}

// ------------------------------------------------------------------
// K3 MFMA: g_bf16 = gelu(hn_bf16 @ W1 + b1). (round-6/7/8 verified)
// ------------------------------------------------------------------
__global__ __launch_bounds__(256) void k3_mfma(
  const float* __restrict__ b1, float* __restrict__ ws)
{
  __shared__ unsigned short aT[2][64*40];
  __shared__ unsigned short bT[2][128*40];
  const unsigned short* hnb = (const unsigned short*)(ws + WS_HNB);
  const unsigned short* w1t = (const unsigned short*)(ws + WS_W1T);
  unsigned short* gb = (unsigned short*)(ws + WS_GB);

  const int tid = threadIdx.x;
  const int M0 = (blockIdx.x >> 3) * 64;
  const int N0 = (blockIdx.x & 7) * 128;
  const int lane = tid & 63;
  const int wid = tid >> 6;
  const int wm = wid >> 1, wn = wid & 1;
  const int m16 = lane & 15, q = lane >> 4;

  const int sa_m = tid >> 2, sa_k = (tid & 3) * 8;
  const int sb_n = tid >> 1, sb_k = (tid & 1) * 16;

  f4 ua, ub0, ub1;
  ua  = *(const f4*)(hnb + (size_t)(M0 + sa_m)*256 + sa_k);
  ub0 = *(const f4*)(w1t + (size_t)(N0 + sb_n)*256 + sb_k);
  ub1 = *(const f4*)(w1t + (size_t)(N0 + sb_n)*256 + sb_k + 8);

  ffrag acc[2][4];
  #pragma unroll
  for (int i=0;i<2;++i)
    #pragma unroll
    for (int j=0;j<4;++j) acc[i][j] = (ffrag){0.f,0.f,0.f,0.f};

  for (int ks=0; ks<8; ++ks){
    const int buf = ks & 1;
    *(f4*)&aT[buf][sa_m*40 + sa_k]     = ua;
    *(f4*)&bT[buf][sb_n*40 + sb_k]     = ub0;
    *(f4*)&bT[buf][sb_n*40 + sb_k + 8] = ub1;
    __syncthreads();
    int kn = (ks < 7) ? ks+1 : 7;
    ua  = *(const f4*)(hnb + (size_t)(M0 + sa_m)*256 + kn*32 + sa_k);
    ub0 = *(const f4*)(w1t + (size_t)(N0 + sb_n)*256 + kn*32 + sb_k);
    ub1 = *(const f4*)(w1t + (size_t)(N0 + sb_n)*256 + kn*32 + sb_k + 8);

    bfrag af[2], bf_[4];
    af[0] = *(const bfrag*)&aT[buf][(wm*32 + m16)*40 + q*8];
    af[1] = *(const bfrag*)&aT[buf][(wm*32 + 16 + m16)*40 + q*8];
    #pragma unroll
    for (int j=0;j<4;++j)
      bf_[j] = *(const bfrag*)&bT[buf][(wn*64 + j*16 + m16)*40 + q*8];
    #pragma unroll
    for (int i=0;i<2;++i)
      #pragma unroll
      for (int j=0;j<4;++j)
        acc[i][j] = __builtin_amdgcn_mfma_f32_16x16x32_bf16(bf_[j], af[i], acc[i][j], 0, 0, 0);
  }

  #pragma unroll
  for (int i=0;i<2;++i){
    const int m = M0 + wm*32 + i*16 + m16;
    #pragma unroll
    for (int j=0;j<4;++j){
      const int n4 = N0 + wn*64 + j*16 + q*4;
      f4 bv = *(const f4*)(b1 + n4);
      ushort4 u;
      u.x = f2bf(gelu_fast(acc[i][j][0] + bv.x));
      u.y = f2bf(gelu_fast(acc[i][j][1] + bv.y));
      u.z = f2bf(gelu_fast(acc[i][j][2] + bv.z));
      u.w = f2bf(gelu_fast(acc[i][j][3] + bv.w));
      *(ushort4*)(gb + (size_t)m*1024 + n4) = u;
    }
  }
}

// ------------------------------------------------------------------
// K4 MFMA: out = htok + g_bf16 @ W2 + b2. (round-6/7/8 verified)
// ------------------------------------------------------------------
__global__ __launch_bounds__(256) void k4_mfma(
  const float* __restrict__ b2, const float* __restrict__ ws_c,
  float* __restrict__ ws, float* __restrict__ out)
{
  __shared__ unsigned short aT[2][32*40];
  __shared__ unsigned short bT[2][64*40];
  const unsigned short* gb  = (const unsigned short*)(ws_c + WS_GB);
  const unsigned short* w2t = (const unsigned short*)(ws_c + WS_W2T);

  const int tid = threadIdx.x;
  const int M0 = (blockIdx.x >> 2) * 32;
  const int N0 = (blockIdx.x & 3) * 64;
  const int lane = tid & 63;
  const int wid = tid >> 6;
  const int wm = wid >> 1, wn = wid & 1;
  const int m16 = lane & 15, q = lane >> 4;

  const int sa_m = tid >> 3, sa_k = (tid & 7) * 4;
  const int sb_n = tid >> 2, sb_k = (tid & 3) * 8;

  ushort4 ua;
  f4 ub;
  ua = *(const ushort4*)(gb  + (size_t)(M0 + sa_m)*1024 + sa_k);
  ub = *(const f4*)(w2t + (size_t)(N0 + sb_n)*1024 + sb_k);

  ffrag acc[2];
  acc[0] = (ffrag){0.f,0.f,0.f,0.f};
  acc[1] = (ffrag){0.f,0.f,0.f,0.f};

  for (int ks=0; ks<32; ++ks){
    const int buf = ks & 1;
    *(ushort4*)&aT[buf][sa_m*40 + sa_k] = ua;
    *(f4*)&bT[buf][sb_n*40 + sb_k]      = ub;
    __syncthreads();
    int kn = (ks < 31) ? ks+1 : 31;
    ua = *(const ushort4*)(gb  + (size_t)(M0 + sa_m)*1024 + kn*32 + sa_k);
    ub = *(const f4*)(w2t + (size_t)(N0 + sb_n)*1024 + kn*32 + sb_k);

    bfrag af, bf0, bf1;
    af  = *(const bfrag*)&aT[buf][(wm*16 + m16)*40 + q*8];
    bf0 = *(const bfrag*)&bT[buf][(wn*32 + m16)*40 + q*8];
    bf1 = *(const bfrag*)&bT[buf][(wn*32 + 16 + m16)*40 + q*8];
    acc[0] = __builtin_amdgcn_mfma_f32_16x16x32_bf16(bf0, af, acc[0], 0, 0, 0);
    acc[1] = __builtin_amdgcn_mfma_f32_16x16x32_bf16(bf1, af, acc[1], 0, 0, 0);
  }

  const int m = M0 + wm*16 + m16;
  #pragma unroll
  for (int j=0;j<2;++j){
    const int n4 = N0 + wn*32 + j*16 + q*4;
    f4 bv = *(const f4*)(b2 + n4);
    f4 hv = *(const f4*)(ws + WS_HT + (size_t)m*256 + n4);
    *(f4*)(out + (size_t)m*256 + n4) =
      make_float4(acc[j][0]+bv.x+hv.x, acc[j][1]+bv.y+hv.y,
                  acc[j][2]+bv.z+hv.z, acc[j][3]+bv.w+hv.w);
  }
}

// ------------------------------------------------------------------
extern "C" void kernel_launch(void* const* d_in, const int* in_sizes, int n_in,
                              void* d_out, int out_size, void* d_ws, size_t ws_size,
                              hipStream_t stream)
{
  const float* x    = (const float*)d_in[0];
  const int*   idx  = (const int*)  d_in[1];
  const float* ctx  = (const float*)d_in[2];
  const float* Wp   = (const float*)d_in[3];
  const float* Bp   = (const float*)d_in[4];
  const float* qemb = (const float*)d_in[5];
  const float* Wkv  = (const float*)d_in[6];
  const float* bkv  = (const float*)d_in[7];
  const float* Wqc  = (const float*)d_in[8];
  const float* bqc  = (const float*)d_in[9];
  const float* Whc  = (const float*)d_in[10];
  const float* bhc  = (const float*)d_in[11];
  const float* Wq   = (const float*)d_in[12];
  const float* Wk   = (const float*)d_in[13];
  const float* Wv   = (const float*)d_in[14];
  const float* Wo   = (const float*)d_in[15];
  const float* W1   = (const float*)d_in[16];
  const float* b1   = (const float*)d_in[17];
  const float* W2   = (const float*)d_in[18];
  const float* b2   = (const float*)d_in[19];
  float* ws  = (float*)d_ws;
  float* out = (float*)d_out;

  hipLaunchKernelGGL(kprep,    dim3(400),  dim3(256), 0, stream,
                     W1, W2, Wv, Wo, ctx, qemb, Wkv, bkv, Wqc, bqc, Whc, bhc, Wq, Wk, ws);
  hipLaunchKernelGGL(k1f_attn, dim3(512),  dim3(256), 0, stream, x, idx, Wp, Bp, ws);
  hipLaunchKernelGGL(k2e_mfma, dim3(256),  dim3(256), 0, stream, qemb, ws);
  hipLaunchKernelGGL(k3_mfma,  dim3(512),  dim3(256), 0, stream, b1, ws);
  hipLaunchKernelGGL(k4_mfma,  dim3(512),  dim3(256), 0, stream, b2, ws, ws, out);
}

// Round 11
// 187.019 us; speedup vs baseline: 1.1591x; 1.1591x over previous
//
#include <hip/hip_runtime.h>
#include <cmath>

#define EPSV 1e-5f
using f4 = float4;

typedef __attribute__((ext_vector_type(8))) short bfrag;   // 8 bf16 (4 VGPRs)
typedef __attribute__((ext_vector_type(4))) float ffrag;   // 4 fp32 acc

// ---- ws layout (float offsets) ----
#define WS_SKV   0           // [4][256]
#define WS_SHKV  1024        // [4][256]
#define WS_SH    2048        // [4][256]
#define WS_SHH   3072        // [4][256]
#define WS_A     4096        // [4][4][256]
#define WS_R     8192        // ushort view: racc partials [2][4096][4][256] bf16
#define WS_HT    4202496     // [4096][256] fp32: o2 then htok (ke in-place)
#define WS_L     5251072     // [2][4096][4] fp32 l partials
#define WS_G     6299648
#define WS_GB    WS_G                   // ushort[4096*1024]  g bf16
#define WS_HNB   (WS_G + 2097152)       // ushort[4096*256]   hn bf16
#define WS_W1T   (WS_G + 2621440)       // ushort[1024*256]   W1^T bf16 [n][k]
#define WS_W2T   (WS_G + 2752512)       // ushort[256*1024]   W2^T bf16 [n][k]
#define WS_MT    (WS_G + 2883584)       // ushort[256*1024]   M^T bf16 [j][h*256+d]

#define FMA8(acc, s, wa, wb) \
  acc[0]=fmaf((s),(wa).x,acc[0]); acc[1]=fmaf((s),(wa).y,acc[1]); \
  acc[2]=fmaf((s),(wa).z,acc[2]); acc[3]=fmaf((s),(wa).w,acc[3]); \
  acc[4]=fmaf((s),(wb).x,acc[4]); acc[5]=fmaf((s),(wb).y,acc[5]); \
  acc[6]=fmaf((s),(wb).z,acc[6]); acc[7]=fmaf((s),(wb).w,acc[7]);

#define DOT8(res, v, wa, wb) \
  res = fmaf((v)[0],(wa).x,res); res = fmaf((v)[1],(wa).y,res); \
  res = fmaf((v)[2],(wa).z,res); res = fmaf((v)[3],(wa).w,res); \
  res = fmaf((v)[4],(wb).x,res); res = fmaf((v)[5],(wb).y,res); \
  res = fmaf((v)[6],(wb).z,res); res = fmaf((v)[7],(wb).w,res);

__device__ __forceinline__ float bfly32(float v){
  v += __shfl_xor(v, 1);  v += __shfl_xor(v, 2);  v += __shfl_xor(v, 4);
  v += __shfl_xor(v, 8);  v += __shfl_xor(v, 16);
  return v;
}

// DPP-based 32-lane allreduce (round-8 verified).
template<int CTRL>
__device__ __forceinline__ float dpp_add(float v){
  int x = __builtin_bit_cast(int, v);
  int y = __builtin_amdgcn_update_dpp(0, x, CTRL, 0xf, 0xf, true);
  return v + __builtin_bit_cast(float, y);
}
__device__ __forceinline__ float red32(float v){
  v = dpp_add<0xB1>(v);
  v = dpp_add<0x4E>(v);
  v = dpp_add<0x124>(v);
  v = dpp_add<0x128>(v);
  v += __shfl_xor(v, 16);
  return v;
}

__device__ __forceinline__ float gelu_fast(float x){
  float z2 = 1.5957691216057308f*(x + 0.044715f*x*x*x);
  return x / (1.0f + __expf(-z2));
}

__device__ __forceinline__ unsigned short f2bf(float x){
  union { float f; unsigned u; } v; v.f = x;
  unsigned r = v.u + 0x7fffu + ((v.u >> 16) & 1u);
  return (unsigned short)(r >> 16);
}
__device__ __forceinline__ float bfu(unsigned short u){
  union { unsigned u; float f; } v; v.u = ((unsigned)u) << 16; return v.f;
}
__device__ __forceinline__ ushort4 comb4(ushort4 a, ushort4 b, float inv){
  ushort4 r;
  r.x = f2bf((bfu(a.x)+bfu(b.x))*inv);
  r.y = f2bf((bfu(a.y)+bfu(b.y))*inv);
  r.z = f2bf((bfu(a.z)+bfu(b.z))*inv);
  r.w = f2bf((bfu(a.w)+bfu(b.w))*inv);
  return r;
}

// ------------------------------------------------------------------
// KPREP: merged weight prep + per-(b,h) setup. (R10 verified)
// blk<64: W1 conv+T; blk<128: W2 conv+T; blk<384: M^T=Wv@Wo;
// blk>=384 (16 blocks): k0_all body. grid=400, block=256.
// ------------------------------------------------------------------
__global__ __launch_bounds__(256) void kprep(
  const float* __restrict__ W1, const float* __restrict__ W2,
  const float* __restrict__ Wv, const float* __restrict__ Wo,
  const float* __restrict__ ctx, const float* __restrict__ q_emb,
  const float* __restrict__ Wkv, const float* __restrict__ bkv,
  const float* __restrict__ Wqc, const float* __restrict__ bqc,
  const float* __restrict__ Whc, const float* __restrict__ bhc,
  const float* __restrict__ Wq,  const float* __restrict__ Wk,
  float* __restrict__ ws)
{
  const int tid = threadIdx.x;
  int blk = blockIdx.x;
  __shared__ union {
    unsigned short lt[64][68];
    struct { float wvs[4*64]; float wos[64*256]; } m;
    struct { float c[64], qn[256], ph[256], qh64[64], red[8]; } z;
  } sm;

  if (blk < 128){
    const float* src; unsigned short* dst; int K, N, K0, N0;
    if (blk < 64){
      src = W1; dst = (unsigned short*)(ws + WS_W1T);
      K = 256; N = 1024; K0 = (blk >> 4)*64; N0 = (blk & 15)*64;
    } else {
      blk -= 64;
      src = W2; dst = (unsigned short*)(ws + WS_W2T);
      K = 1024; N = 256; K0 = (blk >> 2)*64; N0 = (blk & 3)*64;
    }
    #pragma unroll
    for (int i=0;i<4;++i){
      int r = i*16 + (tid>>4);
      int c = (tid&15)*4;
      f4 v = *(const f4*)(src + (size_t)(K0+r)*N + N0 + c);
      sm.lt[r][c]   = f2bf(v.x); sm.lt[r][c+1] = f2bf(v.y);
      sm.lt[r][c+2] = f2bf(v.z); sm.lt[r][c+3] = f2bf(v.w);
    }
    __syncthreads();
    #pragma unroll
    for (int i=0;i<4;++i){
      int n  = i*16 + (tid>>4);
      int kc = (tid&15)*4;
      ushort4 u;
      u.x = sm.lt[kc][n]; u.y = sm.lt[kc+1][n]; u.z = sm.lt[kc+2][n]; u.w = sm.lt[kc+3][n];
      *(ushort4*)(dst + (size_t)(N0+n)*K + K0 + kc) = u;
    }
  } else if (blk < 384){
    blk -= 128;
    const int h   = blk >> 6;
    const int dg4 = blk & 63;
    {
      int d = tid >> 6, e = tid & 63;
      sm.m.wvs[d*64+e] = Wv[(size_t)(dg4*4 + d)*256 + h*64 + e];
    }
    {
      int e = tid >> 2, c = (tid & 3)*64;
      const float* src = Wo + (size_t)(h*64 + e)*256 + c;
      #pragma unroll
      for (int i=0;i<16;++i)
        *(f4*)&sm.m.wos[e*256 + c + i*4] = *(const f4*)(src + i*4);
    }
    __syncthreads();
    float acc[4] = {};
    for (int e=0;e<64;++e){
      float wo = sm.m.wos[e*256 + tid];
      acc[0] = fmaf(sm.m.wvs[0*64+e], wo, acc[0]);
      acc[1] = fmaf(sm.m.wvs[1*64+e], wo, acc[1]);
      acc[2] = fmaf(sm.m.wvs[2*64+e], wo, acc[2]);
      acc[3] = fmaf(sm.m.wvs[3*64+e], wo, acc[3]);
    }
    unsigned short* Mt = (unsigned short*)(ws + WS_MT);
    ushort4 u;
    u.x = f2bf(acc[0]); u.y = f2bf(acc[1]); u.z = f2bf(acc[2]); u.w = f2bf(acc[3]);
    *(ushort4*)(Mt + (size_t)tid*1024 + h*256 + dg4*4) = u;
  } else {
    blk -= 384;
    const int b = blk >> 2, h = blk & 3;
    if (tid < 64) sm.z.c[tid] = ctx[b*64 + tid];
    __syncthreads();

    float skv = bkv[tid],      shkv = bkv[256+tid];
    float sq  = bqc[tid],      shq  = bqc[256+tid];
    float sh  = bhc[tid],      shh  = bhc[256+tid];
    #pragma unroll 8
    for (int j=0;j<64;++j){
      float cj = sm.z.c[j];
      skv  = fmaf(cj, Wkv[j*512 + tid],       skv);
      shkv = fmaf(cj, Wkv[j*512 + 256 + tid], shkv);
      sq   = fmaf(cj, Wqc[j*512 + tid],       sq);
      shq  = fmaf(cj, Wqc[j*512 + 256 + tid], shq);
      sh   = fmaf(cj, Whc[j*512 + tid],       sh);
      shh  = fmaf(cj, Whc[j*512 + 256 + tid], shh);
    }
    if (h == 0){
      ws[WS_SKV  + b*256 + tid] = skv;
      ws[WS_SHKV + b*256 + tid] = shkv;
      ws[WS_SH   + b*256 + tid] = sh;
      ws[WS_SHH  + b*256 + tid] = shh;
    }

    float qe = q_emb[tid];
    float s1r = qe, s2r = qe*qe;
    for (int mm=1;mm<64;mm<<=1){ s1r += __shfl_xor(s1r,mm); s2r += __shfl_xor(s2r,mm); }
    int wv = tid>>6, ln = tid&63;
    if (ln==0){ sm.z.red[wv*2]=s1r; sm.z.red[wv*2+1]=s2r; }
    __syncthreads();
    float S1 = sm.z.red[0]+sm.z.red[2]+sm.z.red[4]+sm.z.red[6];
    float S2 = sm.z.red[1]+sm.z.red[3]+sm.z.red[5]+sm.z.red[7];
    float mean = S1*(1.0f/256.0f);
    float var  = S2*(1.0f/256.0f) - mean*mean;
    float rs   = rsqrtf(var + EPSV);
    sm.z.qn[tid] = (qe-mean)*rs*(1.0f+sq) + shq;
    __syncthreads();

    {
      const int t = tid & 63, ks = tid >> 6;
      float p = 0.f;
      const float* wq = Wq + (size_t)(ks*64)*256 + h*64 + t;
      #pragma unroll 8
      for (int d=0; d<64; ++d) p = fmaf(sm.z.qn[ks*64+d], wq[d*256], p);
      sm.z.ph[tid] = p;
    }
    __syncthreads();
    if (tid < 64) sm.z.qh64[tid] = sm.z.ph[tid] + sm.z.ph[64+tid] + sm.z.ph[128+tid] + sm.z.ph[192+tid];
    __syncthreads();

    {
      float a = 0.f;
      const float* wkr = Wk + (size_t)tid*256 + h*64;
      #pragma unroll
      for (int e4=0; e4<16; ++e4){
        f4 wv4 = *(const f4*)(wkr + e4*4);
        a = fmaf(sm.z.qh64[e4*4+0], wv4.x, a);
        a = fmaf(sm.z.qh64[e4*4+1], wv4.y, a);
        a = fmaf(sm.z.qh64[e4*4+2], wv4.z, a);
        a = fmaf(sm.z.qh64[e4*4+3], wv4.w, a);
      }
      ws[WS_A + b*1024 + h*256 + tid] = 0.125f*a;
    }
  }
}

// ------------------------------------------------------------------
// K1F v4: token-pairing. 16 tokens per block (thread handles t, t+8
// with one W read), 16 f per block (2 f-halves), grid=512. (R10 verified)
// ------------------------------------------------------------------
__global__ __launch_bounds__(256,2) void k1f_attn(
  const float* __restrict__ x, const int* __restrict__ idx,
  const float* __restrict__ Wp, const float* __restrict__ Bp,
  float* __restrict__ ws)
{
  __shared__ float xs[4096];      // [16 t][256]
  __shared__ float wls[4096];     // [2 f][8 i][256 d]

  const int tid = threadIdx.x;
  const int p0  = (blockIdx.x >> 1) * 16;
  const int half= blockIdx.x & 1;
  const int f0  = half * 16;
  const int b   = p0 >> 10;
  const int t   = tid >> 5;
  const int dg  = tid & 31;
  const int dA  = 4*dg, dB = 128 + 4*dg;

  {
    const float* xg = x + (size_t)p0*256 + tid*8;
    f4 a  = *(const f4*)xg;
    f4 bq = *(const f4*)(xg + 4);
    *(f4*)&xs[tid*8]     = a;
    *(f4*)&xs[tid*8 + 4] = bq;
    f4 a2  = *(const f4*)(xg + 2048);
    f4 bq2 = *(const f4*)(xg + 2048 + 4);
    *(f4*)&xs[2048 + tid*8]     = a2;
    *(f4*)&xs[2048 + tid*8 + 4] = bq2;
  }
  f4 Ar[4][2];
  #pragma unroll
  for (int h=0;h<4;++h){
    Ar[h][0] = *(const f4*)(ws + WS_A + b*1024 + h*256 + dA);
    Ar[h][1] = *(const f4*)(ws + WS_A + b*1024 + h*256 + dB);
  }

  f4 skA = *(const f4*)(ws + WS_SKV  + b*256 + dA);
  f4 skB = *(const f4*)(ws + WS_SKV  + b*256 + dB);
  f4 shA = *(const f4*)(ws + WS_SHKV + b*256 + dA);
  f4 shB = *(const f4*)(ws + WS_SHKV + b*256 + dB);
  float coef[8] = {1.f+skA.x,1.f+skA.y,1.f+skA.z,1.f+skA.w,
                   1.f+skB.x,1.f+skB.y,1.f+skB.z,1.f+skB.w};
  float shk[8]  = {shA.x,shA.y,shA.z,shA.w, shB.x,shB.y,shB.z,shB.w};

  int r0 = idx[f0], r1 = idx[f0+1];
  f4 u0 = *(const f4*)(Wp + (size_t)r0*2048 + tid*8);
  f4 u1 = *(const f4*)(Wp + (size_t)r0*2048 + tid*8 + 4);
  f4 u2 = *(const f4*)(Wp + (size_t)r1*2048 + tid*8);
  f4 u3 = *(const f4*)(Wp + (size_t)r1*2048 + tid*8 + 4);

  float l[2][4] = {};
  float racc[2][4][8] = {};

  for (int fi = 0; fi < 8; ++fi){
    const int f = f0 + fi*2;
    __syncthreads();
    wls[0*256+tid]=u0.x; wls[1*256+tid]=u0.y; wls[2*256+tid]=u0.z; wls[3*256+tid]=u0.w;
    wls[4*256+tid]=u1.x; wls[5*256+tid]=u1.y; wls[6*256+tid]=u1.z; wls[7*256+tid]=u1.w;
    wls[2048+0*256+tid]=u2.x; wls[2048+1*256+tid]=u2.y;
    wls[2048+2*256+tid]=u2.z; wls[2048+3*256+tid]=u2.w;
    wls[2048+4*256+tid]=u3.x; wls[2048+5*256+tid]=u3.y;
    wls[2048+6*256+tid]=u3.z; wls[2048+7*256+tid]=u3.w;
    __syncthreads();

    f4 ba0 = *(const f4*)(Bp + (size_t)r0*256 + dA);
    f4 bb0 = *(const f4*)(Bp + (size_t)r0*256 + dB);
    f4 ba1 = *(const f4*)(Bp + (size_t)r1*256 + dA);
    f4 bb1 = *(const f4*)(Bp + (size_t)r1*256 + dB);

    const int fn = (fi < 7) ? f + 2 : f0;
    int rn0 = idx[fn], rn1 = idx[fn+1];
    u0 = *(const f4*)(Wp + (size_t)rn0*2048 + tid*8);
    u1 = *(const f4*)(Wp + (size_t)rn0*2048 + tid*8 + 4);
    u2 = *(const f4*)(Wp + (size_t)rn1*2048 + tid*8);
    u3 = *(const f4*)(Wp + (size_t)rn1*2048 + tid*8 + 4);

    #pragma unroll
    for (int sub=0; sub<2; ++sub){
      const float* wrow = wls + sub*2048;
      const int fc = f + sub;
      f4 ba = sub ? ba1 : ba0;
      f4 bb = sub ? bb1 : bb0;

      float xf0[8], xf1[8];
      {
        f4 xa = *(const f4*)&xs[t*256 + fc*8];
        f4 xb = *(const f4*)&xs[t*256 + fc*8 + 4];
        xf0[0]=xa.x; xf0[1]=xa.y; xf0[2]=xa.z; xf0[3]=xa.w;
        xf0[4]=xb.x; xf0[5]=xb.y; xf0[6]=xb.z; xf0[7]=xb.w;
        f4 xc = *(const f4*)&xs[(t+8)*256 + fc*8];
        f4 xd = *(const f4*)&xs[(t+8)*256 + fc*8 + 4];
        xf1[0]=xc.x; xf1[1]=xc.y; xf1[2]=xc.z; xf1[3]=xc.w;
        xf1[4]=xd.x; xf1[5]=xd.y; xf1[6]=xd.z; xf1[7]=xd.w;
      }

      float val[2][8] = {};
      #pragma unroll
      for (int i=0;i<8;++i){
        f4 wa  = *(const f4*)&wrow[i*256 + dA];
        f4 wbv = *(const f4*)&wrow[i*256 + dB];
        FMA8(val[0], xf0[i], wa, wbv);
        FMA8(val[1], xf1[i], wa, wbv);
      }

      float off[8] = {shk[0]+ba.x, shk[1]+ba.y, shk[2]+ba.z, shk[3]+ba.w,
                      shk[4]+bb.x, shk[5]+bb.y, shk[6]+bb.z, shk[7]+bb.w};

      #pragma unroll
      for (int tt=0; tt<2; ++tt){
        float s=0.f, ss=0.f;
        #pragma unroll
        for (int jj=0;jj<8;++jj){ s += val[tt][jj]; ss = fmaf(val[tt][jj],val[tt][jj],ss); }
        s = red32(s); ss = red32(ss);
        float mean = s*(1.f/256.f);
        float var  = ss*(1.f/256.f) - mean*mean;
        float rsg  = rsqrtf(var + EPSV);
        float mrs  = mean*rsg;

        float kvl[8];
        #pragma unroll
        for (int jj=0;jj<8;++jj)
          kvl[jj] = fmaf(fmaf(val[tt][jj], rsg, -mrs), coef[jj], off[jj]);

        #pragma unroll
        for (int h=0;h<4;++h){
          float lg = 0.f;
          DOT8(lg, kvl, Ar[h][0], Ar[h][1]);
          lg = red32(lg);
          float pp = __expf(lg);
          l[tt][h] += pp;
          #pragma unroll
          for (int jj=0;jj<8;++jj)
            racc[tt][h][jj] = fmaf(pp, kvl[jj], racc[tt][h][jj]);
        }
      }
    }
    r0 = rn0; r1 = rn1;
  }

  unsigned short* Pr = (unsigned short*)(ws + WS_R);
  #pragma unroll
  for (int tt=0; tt<2; ++tt){
    size_t base = (size_t)(half*4096 + p0 + t + tt*8) * 1024;
    #pragma unroll
    for (int h=0;h<4;++h){
      ushort4 ua, ub;
      ua.x=f2bf(racc[tt][h][0]); ua.y=f2bf(racc[tt][h][1]);
      ua.z=f2bf(racc[tt][h][2]); ua.w=f2bf(racc[tt][h][3]);
      ub.x=f2bf(racc[tt][h][4]); ub.y=f2bf(racc[tt][h][5]);
      ub.z=f2bf(racc[tt][h][6]); ub.w=f2bf(racc[tt][h][7]);
      *(ushort4*)(Pr + base + h*256 + dA) = ua;
      *(ushort4*)(Pr + base + h*256 + dB) = ub;
    }
  }
  if (dg == 0){
    float* Lp = ws + WS_L;
    #pragma unroll
    for (int tt=0; tt<2; ++tt)
      #pragma unroll
      for (int h=0;h<4;++h)
        Lp[(size_t)(half*4096 + p0 + t + tt*8)*4 + h] = l[tt][h];
  }
}

// ------------------------------------------------------------------
// K2G (R8-verified): o2 = ((P0+P1)/l)_bf16 @ Mt^T -> fp32 WS_HT.
// Combine folded into A-staging. grid=512 (128 M x 4 N).
// ------------------------------------------------------------------
__global__ __launch_bounds__(256) void k2g_mfma(float* __restrict__ ws)
{
  __shared__ unsigned short aT[2][32*40];
  __shared__ unsigned short bT[2][64*40];
  __shared__ float invs[128];            // [32 t][4 h]
  const unsigned short* P0 = (const unsigned short*)(ws + WS_R);
  const unsigned short* P1 = P0 + 4194304;
  const unsigned short* mt = (const unsigned short*)(ws + WS_MT);
  const float* Lp = ws + WS_L;

  const int tid = threadIdx.x;
  const int M0 = (blockIdx.x >> 2) * 32;
  const int N0 = (blockIdx.x & 3) * 64;
  const int lane = tid & 63;
  const int wid = tid >> 6;
  const int wm = wid >> 1, wn = wid & 1;
  const int m16 = lane & 15, q = lane >> 4;

  const int sa_m = tid >> 3, sa_k = (tid & 7) * 4;
  const int sb_n = tid >> 2, sb_k = (tid & 3) * 8;

  if (tid < 128){
    int lt = tid >> 2, h = tid & 3;
    invs[tid] = 1.f / (Lp[(size_t)(M0 + lt)*4 + h] +
                       Lp[(size_t)(4096 + M0 + lt)*4 + h]);
  }

  ushort4 ua0 = *(const ushort4*)(P0 + (size_t)(M0 + sa_m)*1024 + sa_k);
  ushort4 ua1 = *(const ushort4*)(P1 + (size_t)(M0 + sa_m)*1024 + sa_k);
  f4 ub = *(const f4*)(mt + (size_t)(N0 + sb_n)*1024 + sb_k);
  __syncthreads();   // invs visible before first staging write

  ffrag acc[2];
  acc[0] = (ffrag){0.f,0.f,0.f,0.f};
  acc[1] = (ffrag){0.f,0.f,0.f,0.f};

  for (int ks=0; ks<32; ++ks){
    const int buf = ks & 1;
    float inv = invs[sa_m*4 + (ks >> 3)];
    *(ushort4*)&aT[buf][sa_m*40 + sa_k] = comb4(ua0, ua1, inv);
    *(f4*)&bT[buf][sb_n*40 + sb_k]      = ub;
    __syncthreads();
    int kn = (ks < 31) ? ks+1 : 31;
    ua0 = *(const ushort4*)(P0 + (size_t)(M0 + sa_m)*1024 + kn*32 + sa_k);
    ua1 = *(const ushort4*)(P1 + (size_t)(M0 + sa_m)*1024 + kn*32 + sa_k);
    ub  = *(const f4*)(mt + (size_t)(N0 + sb_n)*1024 + kn*32 + sb_k);

    bfrag af, bf0, bf1;
    af  = *(const bfrag*)&aT[buf][(wm*16 + m16)*40 + q*8];
    bf0 = *(const bfrag*)&bT[buf][(wn*32 + m16)*40 + q*8];
    bf1 = *(const bfrag*)&bT[buf][(wn*32 + 16 + m16)*40 + q*8];
    acc[0] = __builtin_amdgcn_mfma_f32_16x16x32_bf16(bf0, af, acc[0], 0, 0, 0);
    acc[1] = __builtin_amdgcn_mfma_f32_16x16x32_bf16(bf1, af, acc[1], 0, 0, 0);
  }

  const int m = M0 + wm*16 + m16;
  #pragma unroll
  for (int j=0;j<2;++j){
    const int n4 = N0 + wn*32 + j*16 + q*4;
    *(f4*)(ws + WS_HT + (size_t)m*256 + n4) =
      make_float4(acc[j][0], acc[j][1], acc[j][2], acc[j][3]);
  }
}

// ------------------------------------------------------------------
// KE (R7/R8-verified): htok = o2 + q_emb (in-place WS_HT),
// hn = CLN(htok) -> bf16 HNB. grid=512 (8 tokens), block=256.
// ------------------------------------------------------------------
__global__ __launch_bounds__(256) void ke_ln(
  const float* __restrict__ q_emb, float* __restrict__ ws)
{
  const int tid = threadIdx.x;
  const int p0 = blockIdx.x * 8;
  const int b  = p0 >> 10;
  const int tq = tid >> 5, jq = tid & 31;
  const int cA = 4*jq, cB = 128 + 4*jq;

  float* op = ws + WS_HT + (size_t)(p0+tq)*256;
  f4 oA = *(const f4*)(op + cA);
  f4 oB = *(const f4*)(op + cB);
  f4 qA = *(const f4*)(q_emb + cA);
  f4 qB = *(const f4*)(q_emb + cB);
  float ht[8] = {oA.x+qA.x, oA.y+qA.y, oA.z+qA.z, oA.w+qA.w,
                 oB.x+qB.x, oB.y+qB.y, oB.z+qB.z, oB.w+qB.w};
  float s=0.f, ss=0.f;
  #pragma unroll
  for (int jj=0;jj<8;++jj){ s += ht[jj]; ss = fmaf(ht[jj],ht[jj],ss); }
  s = bfly32(s); ss = bfly32(ss);
  float mean = s*(1.f/256.f);
  float var  = ss*(1.f/256.f) - mean*mean;
  float rsg  = rsqrtf(var + EPSV);
  f4 sH0 = *(const f4*)(ws + WS_SH  + b*256 + cA);
  f4 sH1 = *(const f4*)(ws + WS_SH  + b*256 + cB);
  f4 hH0 = *(const f4*)(ws + WS_SHH + b*256 + cA);
  f4 hH1 = *(const f4*)(ws + WS_SHH + b*256 + cB);
  float sHv[8]  = {sH0.x,sH0.y,sH0.z,sH0.w, sH1.x,sH1.y,sH1.z,sH1.w};
  float hHv[8]  = {hH0.x,hH0.y,hH0.z,hH0.w, hH1.x,hH1.y,hH1.z,hH1.w};
  float hnv[8];
  #pragma unroll
  for (int jj=0;jj<8;++jj)
    hnv[jj] = (ht[jj]-mean)*rsg*(1.f+sHv[jj]) + hHv[jj];

  *(f4*)(op+cA) = make_float4(ht[0],ht[1],ht[2],ht[3]);
  *(f4*)(op+cB) = make_float4(ht[4],ht[5],ht[6],ht[7]);
  unsigned short* hnb = (unsigned short*)(ws + WS_HNB);
  ushort4 uA, uB;
  uA.x=f2bf(hnv[0]); uA.y=f2bf(hnv[1]); uA.z=f2bf(hnv[2]); uA.w=f2bf(hnv[3]);
  uB.x=f2bf(hnv[4]); uB.y=f2bf(hnv[5]); uB.z=f2bf(hnv[6]); uB.w=f2bf(hnv[7]);
  *(ushort4*)(hnb + (size_t)(p0+tq)*256 + cA) = uA;
  *(ushort4*)(hnb + (size_t)(p0+tq)*256 + cB) = uB;
}

// ------------------------------------------------------------------
// K3 MFMA: g_bf16 = gelu(hn_bf16 @ W1 + b1). (round-6..10 verified)
// ------------------------------------------------------------------
__global__ __launch_bounds__(256) void k3_mfma(
  const float* __restrict__ b1, float* __restrict__ ws)
{
  __shared__ unsigned short aT[2][64*40];
  __shared__ unsigned short bT[2][128*40];
  const unsigned short* hnb = (const unsigned short*)(ws + WS_HNB);
  const unsigned short* w1t = (const unsigned short*)(ws + WS_W1T);
  unsigned short* gb = (unsigned short*)(ws + WS_GB);

  const int tid = threadIdx.x;
  const int M0 = (blockIdx.x >> 3) * 64;
  const int N0 = (blockIdx.x & 7) * 128;
  const int lane = tid & 63;
  const int wid = tid >> 6;
  const int wm = wid >> 1, wn = wid & 1;
  const int m16 = lane & 15, q = lane >> 4;

  const int sa_m = tid >> 2, sa_k = (tid & 3) * 8;
  const int sb_n = tid >> 1, sb_k = (tid & 1) * 16;

  f4 ua, ub0, ub1;
  ua  = *(const f4*)(hnb + (size_t)(M0 + sa_m)*256 + sa_k);
  ub0 = *(const f4*)(w1t + (size_t)(N0 + sb_n)*256 + sb_k);
  ub1 = *(const f4*)(w1t + (size_t)(N0 + sb_n)*256 + sb_k + 8);

  ffrag acc[2][4];
  #pragma unroll
  for (int i=0;i<2;++i)
    #pragma unroll
    for (int j=0;j<4;++j) acc[i][j] = (ffrag){0.f,0.f,0.f,0.f};

  for (int ks=0; ks<8; ++ks){
    const int buf = ks & 1;
    *(f4*)&aT[buf][sa_m*40 + sa_k]     = ua;
    *(f4*)&bT[buf][sb_n*40 + sb_k]     = ub0;
    *(f4*)&bT[buf][sb_n*40 + sb_k + 8] = ub1;
    __syncthreads();
    int kn = (ks < 7) ? ks+1 : 7;
    ua  = *(const f4*)(hnb + (size_t)(M0 + sa_m)*256 + kn*32 + sa_k);
    ub0 = *(const f4*)(w1t + (size_t)(N0 + sb_n)*256 + kn*32 + sb_k);
    ub1 = *(const f4*)(w1t + (size_t)(N0 + sb_n)*256 + kn*32 + sb_k + 8);

    bfrag af[2], bf_[4];
    af[0] = *(const bfrag*)&aT[buf][(wm*32 + m16)*40 + q*8];
    af[1] = *(const bfrag*)&aT[buf][(wm*32 + 16 + m16)*40 + q*8];
    #pragma unroll
    for (int j=0;j<4;++j)
      bf_[j] = *(const bfrag*)&bT[buf][(wn*64 + j*16 + m16)*40 + q*8];
    #pragma unroll
    for (int i=0;i<2;++i)
      #pragma unroll
      for (int j=0;j<4;++j)
        acc[i][j] = __builtin_amdgcn_mfma_f32_16x16x32_bf16(bf_[j], af[i], acc[i][j], 0, 0, 0);
  }

  #pragma unroll
  for (int i=0;i<2;++i){
    const int m = M0 + wm*32 + i*16 + m16;
    #pragma unroll
    for (int j=0;j<4;++j){
      const int n4 = N0 + wn*64 + j*16 + q*4;
      f4 bv = *(const f4*)(b1 + n4);
      ushort4 u;
      u.x = f2bf(gelu_fast(acc[i][j][0] + bv.x));
      u.y = f2bf(gelu_fast(acc[i][j][1] + bv.y));
      u.z = f2bf(gelu_fast(acc[i][j][2] + bv.z));
      u.w = f2bf(gelu_fast(acc[i][j][3] + bv.w));
      *(ushort4*)(gb + (size_t)m*1024 + n4) = u;
    }
  }
}

// ------------------------------------------------------------------
// K4 MFMA: out = htok + g_bf16 @ W2 + b2. (round-6..10 verified)
// ------------------------------------------------------------------
__global__ __launch_bounds__(256) void k4_mfma(
  const float* __restrict__ b2, const float* __restrict__ ws_c,
  float* __restrict__ ws, float* __restrict__ out)
{
  __shared__ unsigned short aT[2][32*40];
  __shared__ unsigned short bT[2][64*40];
  const unsigned short* gb  = (const unsigned short*)(ws_c + WS_GB);
  const unsigned short* w2t = (const unsigned short*)(ws_c + WS_W2T);

  const int tid = threadIdx.x;
  const int M0 = (blockIdx.x >> 2) * 32;
  const int N0 = (blockIdx.x & 3) * 64;
  const int lane = tid & 63;
  const int wid = tid >> 6;
  const int wm = wid >> 1, wn = wid & 1;
  const int m16 = lane & 15, q = lane >> 4;

  const int sa_m = tid >> 3, sa_k = (tid & 7) * 4;
  const int sb_n = tid >> 2, sb_k = (tid & 3) * 8;

  ushort4 ua;
  f4 ub;
  ua = *(const ushort4*)(gb  + (size_t)(M0 + sa_m)*1024 + sa_k);
  ub = *(const f4*)(w2t + (size_t)(N0 + sb_n)*1024 + sb_k);

  ffrag acc[2];
  acc[0] = (ffrag){0.f,0.f,0.f,0.f};
  acc[1] = (ffrag){0.f,0.f,0.f,0.f};

  for (int ks=0; ks<32; ++ks){
    const int buf = ks & 1;
    *(ushort4*)&aT[buf][sa_m*40 + sa_k] = ua;
    *(f4*)&bT[buf][sb_n*40 + sb_k]      = ub;
    __syncthreads();
    int kn = (ks < 31) ? ks+1 : 31;
    ua = *(const ushort4*)(gb  + (size_t)(M0 + sa_m)*1024 + kn*32 + sa_k);
    ub = *(const f4*)(w2t + (size_t)(N0 + sb_n)*1024 + kn*32 + sb_k);

    bfrag af, bf0, bf1;
    af  = *(const bfrag*)&aT[buf][(wm*16 + m16)*40 + q*8];
    bf0 = *(const bfrag*)&bT[buf][(wn*32 + m16)*40 + q*8];
    bf1 = *(const bfrag*)&bT[buf][(wn*32 + 16 + m16)*40 + q*8];
    acc[0] = __builtin_amdgcn_mfma_f32_16x16x32_bf16(bf0, af, acc[0], 0, 0, 0);
    acc[1] = __builtin_amdgcn_mfma_f32_16x16x32_bf16(bf1, af, acc[1], 0, 0, 0);
  }

  const int m = M0 + wm*16 + m16;
  #pragma unroll
  for (int j=0;j<2;++j){
    const int n4 = N0 + wn*32 + j*16 + q*4;
    f4 bv = *(const f4*)(b2 + n4);
    f4 hv = *(const f4*)(ws + WS_HT + (size_t)m*256 + n4);
    *(f4*)(out + (size_t)m*256 + n4) =
      make_float4(acc[j][0]+bv.x+hv.x, acc[j][1]+bv.y+hv.y,
                  acc[j][2]+bv.z+hv.z, acc[j][3]+bv.w+hv.w);
  }
}

// ------------------------------------------------------------------
extern "C" void kernel_launch(void* const* d_in, const int* in_sizes, int n_in,
                              void* d_out, int out_size, void* d_ws, size_t ws_size,
                              hipStream_t stream)
{
  const float* x    = (const float*)d_in[0];
  const int*   idx  = (const int*)  d_in[1];
  const float* ctx  = (const float*)d_in[2];
  const float* Wp   = (const float*)d_in[3];
  const float* Bp   = (const float*)d_in[4];
  const float* qemb = (const float*)d_in[5];
  const float* Wkv  = (const float*)d_in[6];
  const float* bkv  = (const float*)d_in[7];
  const float* Wqc  = (const float*)d_in[8];
  const float* bqc  = (const float*)d_in[9];
  const float* Whc  = (const float*)d_in[10];
  const float* bhc  = (const float*)d_in[11];
  const float* Wq   = (const float*)d_in[12];
  const float* Wk   = (const float*)d_in[13];
  const float* Wv   = (const float*)d_in[14];
  const float* Wo   = (const float*)d_in[15];
  const float* W1   = (const float*)d_in[16];
  const float* b1   = (const float*)d_in[17];
  const float* W2   = (const float*)d_in[18];
  const float* b2   = (const float*)d_in[19];
  float* ws  = (float*)d_ws;
  float* out = (float*)d_out;

  hipLaunchKernelGGL(kprep,    dim3(400),  dim3(256), 0, stream,
                     W1, W2, Wv, Wo, ctx, qemb, Wkv, bkv, Wqc, bqc, Whc, bhc, Wq, Wk, ws);
  hipLaunchKernelGGL(k1f_attn, dim3(512),  dim3(256), 0, stream, x, idx, Wp, Bp, ws);
  hipLaunchKernelGGL(k2g_mfma, dim3(512),  dim3(256), 0, stream, ws);
  hipLaunchKernelGGL(ke_ln,    dim3(512),  dim3(256), 0, stream, qemb, ws);
  hipLaunchKernelGGL(k3_mfma,  dim3(512),  dim3(256), 0, stream, b1, ws);
  hipLaunchKernelGGL(k4_mfma,  dim3(512),  dim3(256), 0, stream, b2, ws, ws, out);
}